// Round 5
// baseline (108.857 us; speedup 1.0000x reference)
//
#include <hip/hip_runtime.h>

// Dota2Eq3Embed, MFMA version, round 5.
// Per (n, side): v[i][d] = relu(embed[x[n,side,i]][d]); the 8 equivariant
// basis contractions of the rank-1 cube reduce to per-channel tables over
// {v_a v_b v_c, S*pair, S^2*v, S^3}. Tables via 3 bf16 GEMMs
// (mfma_f32_16x16x32_bf16), K=64 over d. Assembly (125-cell relu mean),
// hbar@wout, FC stay f32 VALU.
// Round-5: wout transposed in prep (WT[side][o][ss], b128 loads in phase C),
// assembly split over all 4 waves (wave-uniform cell halves -> PS partials),
// FT pad zeroing folded into Phase A (one barrier fewer).

typedef __attribute__((ext_vector_type(8))) short bf16x8;
typedef __attribute__((ext_vector_type(4))) float f32x4;

#define DEV __device__ __forceinline__

DEV constexpr int pid2(int a, int b) {
  int x = a < b ? a : b;
  int y = a < b ? b : a;
  return x * (9 - x) / 2 + y;            // 15 symmetric pairs
}
DEV constexpr int tid3(int i, int j, int k) {
  int a = i, b = j, c = k, t;
  if (a > b) { t = a; a = b; b = t; }
  if (b > c) { t = b; b = c; c = t; }
  if (a > b) { t = a; a = b; b = t; }
  return a * (a * a - 18 * a + 107) / 6 + (b - a) * (11 - a - b) / 2 + (c - b);
}

DEV ushort f2bf(float f) {            // f32 -> bf16 round-to-nearest-even
  unsigned u = __builtin_bit_cast(unsigned, f);
  return (ushort)((u + 0x7FFFu + ((u >> 16) & 1u)) >> 16);
}

// ---------- prep: coefs -> bf16 CT[side][b][s][d]; wout -> WT[side][o][ss] ----------
__global__ __launch_bounds__(256)
void cvt_prep_kernel(const float* __restrict__ c1, const float* __restrict__ c2,
                     const float* __restrict__ w1, const float* __restrict__ w2,
                     ushort* __restrict__ ct, float* __restrict__ wt, int do_wt) {
  const int idx = blockIdx.x * 256 + threadIdx.x;
  if (idx < 2 * 8 * 128 * 64) {                       // 131072
    const int d    = idx & 63;
    const int s    = (idx >> 6) & 127;
    const int b    = (idx >> 13) & 7;
    const int side = idx >> 16;
    const float* src = side ? c2 : c1;
    ct[idx] = f2bf(src[(d * 128 + s) * 8 + b]);
  } else if (do_wt) {
    const int j = idx - 131072;
    if (j < 2 * 128 * 128) {                          // 32768
      const int ss   = j & 127;
      const int o    = (j >> 7) & 127;
      const int side = j >> 14;
      wt[j] = (side ? w2 : w1)[ss * 128 + o];
    }
  }
}

// FT row map (per side), rows t, cols d (stride 72 bf16, 16B-aligned):
//   rows 0..34  : triples v_a v_b v_c (lex a<=b<=c)   [pad rows 35..47 = 0]
//   rows 48..62 : S * pair_t                          [row 63 = 0]
//   rows 64..68 : S^2 * v_i ;  row 69 : S^3           [rows 70..79 = 0]
// (cols 64..71 are alignment pad, never read by b-frags.)

__global__ __launch_bounds__(256, 2)
void dota2_eq3_mfma(const int* __restrict__ x, const float* __restrict__ embed,
                    const float* __restrict__ bias1, const float* __restrict__ wout1,
                    const float* __restrict__ bout1,
                    const float* __restrict__ bias2, const float* __restrict__ wout2,
                    const float* __restrict__ bout2,
                    const float* __restrict__ fcw, const float* __restrict__ fcb,
                    const ushort* __restrict__ ct, const float* __restrict__ wt,
                    float* __restrict__ out)
{
  __shared__ __align__(16) ushort FT[2][80][72];   // 23040 B
  __shared__ __align__(16) float  OUT[128][100];   // 51200 B
  __shared__ __align__(16) float  PS[2][128];      // assembly partials
  __shared__ __align__(16) float  hbarL[2][128];
  __shared__ __align__(16) float  zL[256];

  const int n   = blockIdx.x;
  const int tid = threadIdx.x;
  const int w   = tid >> 6;       // wave 0..3
  const int l   = tid & 63;
  const int grp = l >> 4;         // 0..3
  const int lc  = l & 15;

  // ---- Phase A: features -> FT bf16 (tid<128: side=(tid>>6)&1, d=tid&63) ----
  if (tid < 128) {
    const int side = tid >> 6;
    const int d = tid & 63;
    const int* xn = x + n * 10 + side * 5;
    float v[5];
    #pragma unroll
    for (int i = 0; i < 5; ++i) v[i] = fmaxf(embed[xn[i] * 64 + d], 0.f);
    const float S  = v[0] + v[1] + v[2] + v[3] + v[4];
    const float S2 = S * S;
    const float S3 = S2 * S;
    float p2[15];
    {
      int c2 = 0;
      #pragma unroll
      for (int a = 0; a < 5; ++a)
        #pragma unroll
        for (int b = a; b < 5; ++b) { p2[c2] = v[a] * v[b]; ++c2; }
    }
    ushort* colp = &FT[side][0][d];          // + row*72
    {
      int c3 = 0;
      #pragma unroll
      for (int a = 0; a < 5; ++a)
        #pragma unroll
        for (int b = a; b < 5; ++b)
          #pragma unroll
          for (int c = b; c < 5; ++c) { colp[c3 * 72] = f2bf(p2[pid2(a, b)] * v[c]); ++c3; }
    }
    #pragma unroll
    for (int t = 0; t < 15; ++t) colp[(48 + t) * 72] = f2bf(S * p2[t]);
    #pragma unroll
    for (int i = 0; i < 5; ++i)  colp[(64 + i) * 72] = f2bf(S2 * v[i]);
    colp[69 * 72] = f2bf(S3);
    // pad rows (read by b-frags, must be zero)
    #pragma unroll
    for (int r = 35; r < 48; ++r) colp[r * 72] = 0;
    colp[63 * 72] = 0;
    #pragma unroll
    for (int r = 70; r < 80; ++r) colp[r * 72] = 0;
  }
  __syncthreads();

  auto bfrag = [&](int side, int t0, int h) -> bf16x8 {
    return *(const bf16x8*)(&FT[side][t0 + lc][32 * h + 8 * grp]);
  };
  auto dwrite = [&](const f32x4& acc, int s0, int colbase, int nvalid) {
    if (lc < nvalid) {
      float* p = &OUT[s0 + 4 * grp][colbase + lc];
      p[0] = acc[0]; p[100] = acc[1]; p[200] = acc[2]; p[300] = acc[3];
    }
  };

  auto do_gemms = [&](int side) {
    const ushort* CTs = ct + side * (8 * 128 * 64);
    auto afrag = [&](int b, int s0, int h) -> bf16x8 {
      const ushort* rp = CTs + (b * 128 + s0 + lc) * 64;
      return *(const bf16x8*)(rp + 32 * h + 8 * grp);
    };
    // GEMM-A: bank0, cols 0..34
    {
      const bf16x8 A00 = afrag(0, 32 * w,      0), A01 = afrag(0, 32 * w,      1);
      const bf16x8 A10 = afrag(0, 32 * w + 16, 0), A11 = afrag(0, 32 * w + 16, 1);
      #pragma unroll
      for (int nt = 0; nt < 3; ++nt) {
        const bf16x8 B0 = bfrag(side, nt * 16, 0), B1 = bfrag(side, nt * 16, 1);
        const int nvalid = (nt == 2) ? 3 : 16;
        f32x4 acc0 = {0.f, 0.f, 0.f, 0.f};
        acc0 = __builtin_amdgcn_mfma_f32_16x16x32_bf16(A00, B0, acc0, 0, 0, 0);
        acc0 = __builtin_amdgcn_mfma_f32_16x16x32_bf16(A01, B1, acc0, 0, 0, 0);
        dwrite(acc0, 32 * w, nt * 16, nvalid);
        f32x4 acc1 = {0.f, 0.f, 0.f, 0.f};
        acc1 = __builtin_amdgcn_mfma_f32_16x16x32_bf16(A10, B0, acc1, 0, 0, 0);
        acc1 = __builtin_amdgcn_mfma_f32_16x16x32_bf16(A11, B1, acc1, 0, 0, 0);
        dwrite(acc1, 32 * w + 16, nt * 16, nvalid);
      }
    }
    // GEMM-B: banks 1..3 x pairs, cols 35 + (b-1)*15
    {
      const bf16x8 B0 = bfrag(side, 48, 0), B1 = bfrag(side, 48, 1);
      #pragma unroll
      for (int b = 1; b <= 3; ++b)
        #pragma unroll
        for (int u = 0; u < 2; ++u) {
          const int s0 = 32 * w + 16 * u;
          const bf16x8 A0 = afrag(b, s0, 0), A1 = afrag(b, s0, 1);
          f32x4 acc = {0.f, 0.f, 0.f, 0.f};
          acc = __builtin_amdgcn_mfma_f32_16x16x32_bf16(A0, B0, acc, 0, 0, 0);
          acc = __builtin_amdgcn_mfma_f32_16x16x32_bf16(A1, B1, acc, 0, 0, 0);
          dwrite(acc, s0, 35 + (b - 1) * 15, 15);
        }
    }
    // GEMM-C: banks 4..6 -> cols 80+(b-4)*5 (5 valid); bank7 -> col 95 (lane 5)
    {
      const bf16x8 B0 = bfrag(side, 64, 0), B1 = bfrag(side, 64, 1);
      #pragma unroll
      for (int b = 4; b <= 6; ++b)
        #pragma unroll
        for (int u = 0; u < 2; ++u) {
          const int s0 = 32 * w + 16 * u;
          const bf16x8 A0 = afrag(b, s0, 0), A1 = afrag(b, s0, 1);
          f32x4 acc = {0.f, 0.f, 0.f, 0.f};
          acc = __builtin_amdgcn_mfma_f32_16x16x32_bf16(A0, B0, acc, 0, 0, 0);
          acc = __builtin_amdgcn_mfma_f32_16x16x32_bf16(A1, B1, acc, 0, 0, 0);
          dwrite(acc, s0, 80 + (b - 4) * 5, 5);
        }
      #pragma unroll
      for (int u = 0; u < 2; ++u) {
        const int s0 = 32 * w + 16 * u;
        const bf16x8 A0 = afrag(7, s0, 0), A1 = afrag(7, s0, 1);
        f32x4 acc = {0.f, 0.f, 0.f, 0.f};
        acc = __builtin_amdgcn_mfma_f32_16x16x32_bf16(A0, B0, acc, 0, 0, 0);
        acc = __builtin_amdgcn_mfma_f32_16x16x32_bf16(A1, B1, acc, 0, 0, 0);
        if (lc == 5) {
          float* p = &OUT[s0 + 4 * grp][95];
          p[0] = acc[0]; p[100] = acc[1]; p[200] = acc[2]; p[300] = acc[3];
        }
      }
    }
  };

  // assembly partial: all 4 waves, g2 = tid>>7 picks cell half (wave-uniform)
  auto do_assembly = [&](int side) {
    const int g2 = tid >> 7;
    const int s  = tid & 127;
    float T[96];
    const f32x4* rp = (const f32x4*)(&OUT[s][0]);
    #pragma unroll
    for (int j = 0; j < 24; ++j) {
      const f32x4 q = rp[j];
      T[4 * j] = q[0]; T[4 * j + 1] = q[1]; T[4 * j + 2] = q[2]; T[4 * j + 3] = q[3];
    }
    const float* bi = side ? bias2 : bias1;
    const float base = T[95] + bi[s];
    float hsum = 0.f;
    auto cell = [&](int c) {
      const int i = c / 25, j = (c / 5) % 5, k = c % 5;
      const float val = base + T[90 + i] + T[85 + j] + T[65 + pid2(i, j)]
                      + T[80 + k] + T[50 + pid2(i, k)] + T[35 + pid2(j, k)]
                      + T[tid3(i, j, k)];
      hsum += fmaxf(val, 0.f);
    };
    if (g2 == 0) {
      #pragma unroll
      for (int c = 0; c < 62; ++c) cell(c);
    } else {
      #pragma unroll
      for (int c = 62; c < 125; ++c) cell(c);
    }
    PS[g2][s] = hsum;
  };

  // ---- side 0 ----
  do_gemms(0);
  __syncthreads();
  do_assembly(0);
  __syncthreads();
  // combine side-0 partials (waves 0-1) overlapped with side-1 GEMMs (all waves)
  if (tid < 128) hbarL[0][tid] = (PS[0][tid] + PS[1][tid]) * (1.f / 125.f);
  do_gemms(1);
  __syncthreads();
  do_assembly(1);
  __syncthreads();
  if (tid < 128) hbarL[1][tid] = (PS[0][tid] + PS[1][tid]) * (1.f / 125.f);
  __syncthreads();

  // ---- Phase C: z = relu(hbar @ wout + bout), per side ----
  {
    const int side = tid >> 7;
    const int o = tid & 127;
    const float* bo = side ? bout2 : bout1;
    float r;
    if (wt != nullptr) {
      const f32x4* wv = (const f32x4*)(wt + (side << 14) + o * 128);
      const f32x4* hv = (const f32x4*)(&hbarL[side][0]);
      float a0 = 0.f, a1 = 0.f, a2 = 0.f, a3 = 0.f;
      #pragma unroll 8
      for (int q = 0; q < 32; ++q) {
        const f32x4 wq = wv[q];
        const f32x4 hq = hv[q];
        a0 = fmaf(hq[0], wq[0], a0);
        a1 = fmaf(hq[1], wq[1], a1);
        a2 = fmaf(hq[2], wq[2], a2);
        a3 = fmaf(hq[3], wq[3], a3);
      }
      r = (a0 + a1) + (a2 + a3);
    } else {
      const float* W = side ? wout2 : wout1;
      const float* hb = &hbarL[side][0];
      float a0 = 0.f, a1 = 0.f, a2 = 0.f, a3 = 0.f;
      #pragma unroll 4
      for (int ss = 0; ss < 128; ss += 4) {
        a0 = fmaf(hb[ss + 0], W[(ss + 0) * 128 + o], a0);
        a1 = fmaf(hb[ss + 1], W[(ss + 1) * 128 + o], a1);
        a2 = fmaf(hb[ss + 2], W[(ss + 2) * 128 + o], a2);
        a3 = fmaf(hb[ss + 3], W[(ss + 3) * 128 + o], a3);
      }
      r = (a0 + a1) + (a2 + a3);
    }
    zL[side * 128 + o] = fmaxf(bo[o] + r, 0.f);
  }
  __syncthreads();

  // ---- Phase D: final FC (256 -> 2), wave 0 ----
  if (tid < 64) {
    const float4 zq = *reinterpret_cast<const float4*>(&zL[tid * 4]);
    const int q = tid * 4;
    float p0 = 0.f, p1 = 0.f;
    p0 = fmaf(zq.x, fcw[(q + 0) * 2 + 0], p0);
    p1 = fmaf(zq.x, fcw[(q + 0) * 2 + 1], p1);
    p0 = fmaf(zq.y, fcw[(q + 1) * 2 + 0], p0);
    p1 = fmaf(zq.y, fcw[(q + 1) * 2 + 1], p1);
    p0 = fmaf(zq.z, fcw[(q + 2) * 2 + 0], p0);
    p1 = fmaf(zq.z, fcw[(q + 2) * 2 + 1], p1);
    p0 = fmaf(zq.w, fcw[(q + 3) * 2 + 0], p0);
    p1 = fmaf(zq.w, fcw[(q + 3) * 2 + 1], p1);
    #pragma unroll
    for (int off = 32; off; off >>= 1) {
      p0 += __shfl_down(p0, off);
      p1 += __shfl_down(p1, off);
    }
    if (tid == 0) {
      out[n * 2 + 0] = p0 + fcb[0];
      out[n * 2 + 1] = p1 + fcb[1];
    }
  }
}

extern "C" void kernel_launch(void* const* d_in, const int* in_sizes, int n_in,
                              void* d_out, int out_size, void* d_ws, size_t ws_size,
                              hipStream_t stream) {
  const int*   x      = (const int*)  d_in[0];
  const float* embed  = (const float*)d_in[1];
  const float* coefs1 = (const float*)d_in[2];
  const float* bias1  = (const float*)d_in[3];
  const float* wout1  = (const float*)d_in[4];
  const float* bout1  = (const float*)d_in[5];
  const float* coefs2 = (const float*)d_in[6];
  const float* bias2  = (const float*)d_in[7];
  const float* wout2  = (const float*)d_in[8];
  const float* bout2  = (const float*)d_in[9];
  const float* fcw    = (const float*)d_in[10];
  const float* fcb    = (const float*)d_in[11];
  float* out  = (float*)d_out;

  ushort* ct = (ushort*)d_ws;                               // 256 KiB
  const int do_wt = (ws_size >= (262144 + 131072)) ? 1 : 0; // +128 KiB WT
  float* wt = do_wt ? (float*)((char*)d_ws + 262144) : nullptr;

  const int batch = in_sizes[0] / 10;                        // x: (B, 2, 5)
  cvt_prep_kernel<<<640, 256, 0, stream>>>(coefs1, coefs2, wout1, wout2, ct, wt, do_wt);
  dota2_eq3_mfma<<<batch, 256, 0, stream>>>(
      x, embed, bias1, wout1, bout1, bias2, wout2, bout2, fcw, fcb, ct, wt, out);
}

// Round 6
// 103.526 us; speedup vs baseline: 1.0515x; 1.0515x over previous
//
#include <hip/hip_runtime.h>

// Dota2Eq3Embed, MFMA version, round 6: one block per (sample, side) unit.
// Per unit: v[i][d] = relu(embed[x[u*5+i]][d]); 8 equivariant basis
// contractions of the rank-1 cube reduce to 96 per-channel tables
// {v_a v_b v_c, S*pair, S^2*v, S^3}; computed as bf16 GEMMs
// (mfma_f32_16x16x32_bf16, K=64 over d) in two s-halves to keep LDS small
// (39424 B -> 4 blocks/CU). 125-cell relu mean + wout projection + per-side
// partial FC -> pbuf; tiny fc_final kernel combines sides.

typedef __attribute__((ext_vector_type(8))) short bf16x8;
typedef __attribute__((ext_vector_type(4))) float f32x4;

#define DEV __device__ __forceinline__

DEV constexpr int pid2(int a, int b) {
  int x = a < b ? a : b;
  int y = a < b ? b : a;
  return x * (9 - x) / 2 + y;            // 15 symmetric pairs
}
DEV constexpr int tid3(int i, int j, int k) {
  int a = i, b = j, c = k, t;
  if (a > b) { t = a; a = b; b = t; }
  if (b > c) { t = b; b = c; c = t; }
  if (a > b) { t = a; a = b; b = t; }
  return a * (a * a - 18 * a + 107) / 6 + (b - a) * (11 - a - b) / 2 + (c - b);
}

DEV ushort f2bf(float f) {            // f32 -> bf16 round-to-nearest-even
  unsigned u = __builtin_bit_cast(unsigned, f);
  return (ushort)((u + 0x7FFFu + ((u >> 16) & 1u)) >> 16);
}

// ---------- prep: coefs -> bf16 CT[side][b][s][d]; wout -> WT[side][o][ss] ----------
__global__ __launch_bounds__(256)
void cvt_prep_kernel(const float* __restrict__ c1, const float* __restrict__ c2,
                     const float* __restrict__ w1, const float* __restrict__ w2,
                     ushort* __restrict__ ct, float* __restrict__ wt, int do_wt) {
  const int idx = blockIdx.x * 256 + threadIdx.x;
  if (idx < 2 * 8 * 128 * 64) {                       // 131072
    const int d    = idx & 63;
    const int s    = (idx >> 6) & 127;
    const int b    = (idx >> 13) & 7;
    const int side = idx >> 16;
    const float* src = side ? c2 : c1;
    ct[idx] = f2bf(src[(d * 128 + s) * 8 + b]);
  } else if (do_wt) {
    const int j = idx - 131072;
    if (j < 2 * 128 * 128) {                          // 32768
      const int ss   = j & 127;
      const int o    = (j >> 7) & 127;
      const int side = j >> 14;
      wt[j] = (side ? w2 : w1)[ss * 128 + o];
    }
  }
}

// FT rows (stride 72 ushort = 144 B, swizzle-free 2-way banks):
//   0..34  triples (lex a<=b<=c)   [35..47 zero]
//   48..62 S*pair                  [63 zero]
//   64..68 S^2*v ; 69 S^3          [70..79 zero]
// OUT cols: 0..34 g0 | 35..49 b1 | 50..64 b2 | 65..79 b3 | 80..84 m4 |
//           85..89 m5 | 90..94 m6 | 95 a7.  Stride 101 -> 2-way banks.

__global__ __launch_bounds__(256, 4)
void dota2_eq3_side(const int* __restrict__ x, const float* __restrict__ embed,
                    const float* __restrict__ bias1, const float* __restrict__ bias2,
                    const float* __restrict__ wout1, const float* __restrict__ wout2,
                    const float* __restrict__ bout1, const float* __restrict__ bout2,
                    const float* __restrict__ fcw,
                    const ushort* __restrict__ ct, const float* __restrict__ wt,
                    float* __restrict__ pbuf)
{
  __shared__ __align__(16) ushort FT[80][72];      // 11520 B
  __shared__ __align__(16) float  OUT[64][101];    // 25856 B
  __shared__ __align__(16) float  scratch[256];    // 1024 B (asm PS / phaseC PS)
  __shared__ __align__(16) float  hbar[128];       // 512 B
  __shared__ __align__(16) float  zL[128];         // 512 B

  const int u    = blockIdx.x;      // unit = sample*2 + side
  const int side = u & 1;
  const int tid  = threadIdx.x;
  const int w    = tid >> 6;
  const int l    = tid & 63;
  const int grp  = l >> 4;
  const int lc   = l & 15;

  // ---- Phase A: features (tid<64, d=tid); others zero the pad rows ----
  if (tid < 64) {
    const int d = tid;
    const int* xn = x + u * 5;
    float v[5];
    #pragma unroll
    for (int i = 0; i < 5; ++i) v[i] = fmaxf(embed[xn[i] * 64 + d], 0.f);
    const float S  = v[0] + v[1] + v[2] + v[3] + v[4];
    const float S2 = S * S;
    const float S3 = S2 * S;
    float p2[15];
    {
      int c2 = 0;
      #pragma unroll
      for (int a = 0; a < 5; ++a)
        #pragma unroll
        for (int b = a; b < 5; ++b) { p2[c2] = v[a] * v[b]; ++c2; }
    }
    ushort* colp = &FT[0][d];               // + row*72
    {
      int c3 = 0;
      #pragma unroll
      for (int a = 0; a < 5; ++a)
        #pragma unroll
        for (int b = a; b < 5; ++b)
          #pragma unroll
          for (int c = b; c < 5; ++c) { colp[c3 * 72] = f2bf(p2[pid2(a, b)] * v[c]); ++c3; }
    }
    #pragma unroll
    for (int t = 0; t < 15; ++t) colp[(48 + t) * 72] = f2bf(S * p2[t]);
    #pragma unroll
    for (int i = 0; i < 5; ++i)  colp[(64 + i) * 72] = f2bf(S2 * v[i]);
    colp[69 * 72] = f2bf(S3);
  } else {
    // zero 24 pad rows x 72 cols = 1728 entries with threads 64..255
    const int idx = tid - 64;
    #pragma unroll
    for (int e0 = 0; e0 < 9; ++e0) {
      const int e = idx + e0 * 192;
      const int r = e / 72;
      const int c = e - r * 72;
      const int row = (r < 13) ? (35 + r) : ((r == 13) ? 63 : (56 + r));
      FT[row][c] = 0;
    }
  }
  __syncthreads();

  const ushort* CTs = ct + side * (8 * 128 * 64);

  auto bfrag = [&](int t0, int kh) -> bf16x8 {
    return *(const bf16x8*)(&FT[t0 + lc][32 * kh + 8 * grp]);
  };
  auto dwrite = [&](const f32x4& acc, int s_local, int colbase, int nvalid) {
    if (lc < nvalid) {
      float* p = &OUT[s_local + 4 * grp][colbase + lc];
      p[0] = acc[0]; p[101] = acc[1]; p[202] = acc[2]; p[303] = acc[3];
    }
  };

  // GEMMs for s-half sh: wave w owns 16 channels, s = 64*sh + 16*w + [0,16)
  auto do_gemms = [&](int sh) {
    const int sg = 64 * sh + 16 * w;
    const int s_local = 16 * w;
    auto afrag = [&](int b, int kh) -> bf16x8 {
      const ushort* rp = CTs + (b * 128 + sg + lc) * 64;
      return *(const bf16x8*)(rp + 32 * kh + 8 * grp);
    };
    // bank0 -> cols 0..34 (3 n-tiles)
    {
      const bf16x8 A0 = afrag(0, 0), A1 = afrag(0, 1);
      #pragma unroll
      for (int nt = 0; nt < 3; ++nt) {
        const bf16x8 B0 = bfrag(nt * 16, 0), B1 = bfrag(nt * 16, 1);
        f32x4 acc = {0.f, 0.f, 0.f, 0.f};
        acc = __builtin_amdgcn_mfma_f32_16x16x32_bf16(A0, B0, acc, 0, 0, 0);
        acc = __builtin_amdgcn_mfma_f32_16x16x32_bf16(A1, B1, acc, 0, 0, 0);
        dwrite(acc, s_local, nt * 16, (nt == 2) ? 3 : 16);
      }
    }
    // banks 1..3 x pairs -> cols 35 + (b-1)*15
    {
      const bf16x8 B0 = bfrag(48, 0), B1 = bfrag(48, 1);
      #pragma unroll
      for (int b = 1; b <= 3; ++b) {
        const bf16x8 A0 = afrag(b, 0), A1 = afrag(b, 1);
        f32x4 acc = {0.f, 0.f, 0.f, 0.f};
        acc = __builtin_amdgcn_mfma_f32_16x16x32_bf16(A0, B0, acc, 0, 0, 0);
        acc = __builtin_amdgcn_mfma_f32_16x16x32_bf16(A1, B1, acc, 0, 0, 0);
        dwrite(acc, s_local, 35 + (b - 1) * 15, 15);
      }
    }
    // banks 4..6 -> cols 80+(b-4)*5; bank7 -> col 95 (B col 5 = S^3 row)
    {
      const bf16x8 B0 = bfrag(64, 0), B1 = bfrag(64, 1);
      #pragma unroll
      for (int b = 4; b <= 6; ++b) {
        const bf16x8 A0 = afrag(b, 0), A1 = afrag(b, 1);
        f32x4 acc = {0.f, 0.f, 0.f, 0.f};
        acc = __builtin_amdgcn_mfma_f32_16x16x32_bf16(A0, B0, acc, 0, 0, 0);
        acc = __builtin_amdgcn_mfma_f32_16x16x32_bf16(A1, B1, acc, 0, 0, 0);
        dwrite(acc, s_local, 80 + (b - 4) * 5, 5);
      }
      const bf16x8 A0 = afrag(7, 0), A1 = afrag(7, 1);
      f32x4 acc = {0.f, 0.f, 0.f, 0.f};
      acc = __builtin_amdgcn_mfma_f32_16x16x32_bf16(A0, B0, acc, 0, 0, 0);
      acc = __builtin_amdgcn_mfma_f32_16x16x32_bf16(A1, B1, acc, 0, 0, 0);
      if (lc == 5) {
        float* p = &OUT[s_local + 4 * grp][95];
        p[0] = acc[0]; p[101] = acc[1]; p[202] = acc[2]; p[303] = acc[3];
      }
    }
  };

  // assembly for s-half sh: 64 channels x 4 cell-quarters (wave-uniform q)
  auto do_asm = [&](int sh) {
    const int ch = tid & 63;
    const int q  = tid >> 6;
    float T[96];
    #pragma unroll
    for (int t = 0; t < 96; ++t) T[t] = OUT[ch][t];
    const float* bi = side ? bias2 : bias1;
    const float base = T[95] + bi[64 * sh + ch];
    float hsum = 0.f;
    auto cell = [&](int c) {
      const int i = c / 25, j = (c / 5) % 5, k = c % 5;
      const float val = base + T[90 + i] + T[85 + j] + T[65 + pid2(i, j)]
                      + T[80 + k] + T[50 + pid2(i, k)] + T[35 + pid2(j, k)]
                      + T[tid3(i, j, k)];
      hsum += fmaxf(val, 0.f);
    };
    if (q == 0) {
      #pragma unroll
      for (int c = 0; c < 31; ++c) cell(c);
    } else if (q == 1) {
      #pragma unroll
      for (int c = 31; c < 62; ++c) cell(c);
    } else if (q == 2) {
      #pragma unroll
      for (int c = 62; c < 93; ++c) cell(c);
    } else {
      #pragma unroll
      for (int c = 93; c < 125; ++c) cell(c);
    }
    scratch[q * 64 + ch] = hsum;
  };

  // ---- s-half 0 ----
  do_gemms(0);
  __syncthreads();
  do_asm(0);
  __syncthreads();
  if (tid < 64)
    hbar[tid] = (scratch[tid] + scratch[64 + tid] + scratch[128 + tid] + scratch[192 + tid])
                * (1.f / 125.f);
  // ---- s-half 1 (gemms overlap the combine above; OUT was fully read) ----
  do_gemms(1);
  __syncthreads();
  do_asm(1);
  __syncthreads();
  if (tid < 64)
    hbar[64 + tid] = (scratch[tid] + scratch[64 + tid] + scratch[128 + tid] + scratch[192 + tid])
                     * (1.f / 125.f);
  __syncthreads();

  // ---- Phase C: z[o] = relu(hbar @ wout + bout); 256 thr, ss-halves ----
  {
    const int o = tid & 127, shh = tid >> 7;
    float r;
    if (wt != nullptr) {
      const f32x4* wv = (const f32x4*)(wt + side * 16384 + o * 128 + shh * 64);
      const f32x4* hv = (const f32x4*)(&hbar[shh * 64]);
      float a0 = 0.f, a1 = 0.f, a2 = 0.f, a3 = 0.f;
      #pragma unroll
      for (int qq = 0; qq < 16; ++qq) {
        const f32x4 wq = wv[qq];
        const f32x4 hq = hv[qq];
        a0 = fmaf(hq[0], wq[0], a0);
        a1 = fmaf(hq[1], wq[1], a1);
        a2 = fmaf(hq[2], wq[2], a2);
        a3 = fmaf(hq[3], wq[3], a3);
      }
      r = (a0 + a1) + (a2 + a3);
    } else {
      const float* W = side ? wout2 : wout1;
      float a0 = 0.f, a1 = 0.f;
      #pragma unroll 8
      for (int ss = 64 * shh; ss < 64 * shh + 64; ss += 2) {
        a0 = fmaf(hbar[ss], W[ss * 128 + o], a0);
        a1 = fmaf(hbar[ss + 1], W[(ss + 1) * 128 + o], a1);
      }
      r = a0 + a1;
    }
    scratch[shh * 128 + o] = r;
  }
  __syncthreads();
  if (tid < 128) {
    const float* bo_ = side ? bout2 : bout1;
    zL[tid] = fmaxf(scratch[tid] + scratch[128 + tid] + bo_[tid], 0.f);
  }
  __syncthreads();

  // ---- partial FC: pbuf[u][c] = sum_o z[o] * fcw[(side*128+o)*2+c] ----
  if (tid < 64) {
    const float z0 = zL[tid], z1 = zL[tid + 64];
    const float* fw = fcw + side * 256;
    float p0 = fmaf(z0, fw[2 * tid],     z1 * fw[2 * tid + 128]);
    float p1 = fmaf(z0, fw[2 * tid + 1], z1 * fw[2 * tid + 129]);
    #pragma unroll
    for (int off = 32; off; off >>= 1) {
      p0 += __shfl_down(p0, off);
      p1 += __shfl_down(p1, off);
    }
    if (tid == 0) {
      pbuf[2 * u + 0] = p0;
      pbuf[2 * u + 1] = p1;
    }
  }
}

// ---------- final: out[n,c] = pbuf[2n][c] + pbuf[2n+1][c] + fcb[c] ----------
__global__ __launch_bounds__(256)
void fc_final(const float* __restrict__ pbuf, const float* __restrict__ fcb,
              float* __restrict__ out, int nout) {
  const int t = blockIdx.x * 256 + threadIdx.x;
  if (t < nout) {
    const int n = t >> 1, c = t & 1;
    out[t] = pbuf[4 * n + c] + pbuf[4 * n + 2 + c] + fcb[c];
  }
}

extern "C" void kernel_launch(void* const* d_in, const int* in_sizes, int n_in,
                              void* d_out, int out_size, void* d_ws, size_t ws_size,
                              hipStream_t stream) {
  const int*   x      = (const int*)  d_in[0];
  const float* embed  = (const float*)d_in[1];
  const float* coefs1 = (const float*)d_in[2];
  const float* bias1  = (const float*)d_in[3];
  const float* wout1  = (const float*)d_in[4];
  const float* bout1  = (const float*)d_in[5];
  const float* coefs2 = (const float*)d_in[6];
  const float* bias2  = (const float*)d_in[7];
  const float* wout2  = (const float*)d_in[8];
  const float* bout2  = (const float*)d_in[9];
  const float* fcw    = (const float*)d_in[10];
  const float* fcb    = (const float*)d_in[11];
  float* out = (float*)d_out;

  // ws layout: pbuf (32 KiB) | CT (256 KiB) | WT (128 KiB, optional)
  float*  pbuf = (float*)d_ws;
  ushort* ct   = (ushort*)((char*)d_ws + 32768);
  const int do_wt = (ws_size >= (size_t)(32768 + 262144 + 131072)) ? 1 : 0;
  float*  wt   = do_wt ? (float*)((char*)d_ws + 32768 + 262144) : nullptr;

  const int batch  = in_sizes[0] / 10;   // x: (B, 2, 5)
  const int nunits = batch * 2;

  cvt_prep_kernel<<<640, 256, 0, stream>>>(coefs1, coefs2, wout1, wout2, ct, wt, do_wt);
  dota2_eq3_side<<<nunits, 256, 0, stream>>>(
      x, embed, bias1, bias2, wout1, wout2, bout1, bout2, fcw, ct, wt, pbuf);
  fc_final<<<(nunits + 255) / 256, 256, 0, stream>>>(pbuf, fcb, out, nunits);
}